// Round 9
// baseline (158.601 us; speedup 1.0000x reference)
//
#include <hip/hip_runtime.h>
#include <hip/hip_bf16.h>
#include <math.h>

#define HDIM 150
#define T1 4          // x-tiles (of 16 reads) per wave in k1

typedef __bf16 bf16x8 __attribute__((ext_vector_type(8)));
typedef __bf16 bf16x4 __attribute__((ext_vector_type(4)));
typedef float  f32x4  __attribute__((ext_vector_type(4)));

__device__ __forceinline__ void async_copy16(const void* g, void* l) {
    __builtin_amdgcn_global_load_lds(
        (const __attribute__((address_space(1))) void*)g,
        (__attribute__((address_space(3))) void*)l, 16, 0, 0);
}

// ---------------------------------------------------------------------------
// k_pack: one block precomputes the per-lane MFMA fragment blob.
// R9 K-slot permutation (divergence-free bin build in k1):
//   A1 slot (q, j) :=  j<4  -> x-feature 4q+j          (W1 row 4q+j)
//                      j==4 -> q0: emb_x (W1 row 16), q1: emb_y (W1 row 17),
//                              q2: bias (b1), q3: zero
//                      j>4  -> zero
// Hidden-unit permutation for the register relay unchanged:
//   tile 2kt   row(4q+r) = hidden 32kt+8q+r
//   tile 2kt+1 row(4q+r) = hidden 32kt+8q+4+r
// Blob (uint4 view): tile i of lane L at blob4[i*64+L].
// Per lane: dwords 0..39 = fA1[10], 40..59 = fA2[5], 60..63 = breg.
// ---------------------------------------------------------------------------
__global__ void k_pack(const float* __restrict__ W1, const float* __restrict__ b1,
                       const float* __restrict__ W2, const float* __restrict__ b2,
                       unsigned int* __restrict__ blob)
{
    __shared__ float sW[4050];   // W1 [18][150] | b1 @2700 | W2 [150][8] @2850

    const int t    = threadIdx.x;
    const int lane = t & 63;
    const int c    = t >> 6;        // dword chunk 0..3
    const int m    = lane & 15;
    const int q    = lane >> 4;

    for (int e = t; e < 2700; e += 256) sW[e] = W1[e];
    for (int e = t; e < 150;  e += 256) sW[2700 + e] = b1[e];
    for (int e = t; e < 1200; e += 256) sW[2850 + e] = W2[e];
    __syncthreads();

    for (int d = c * 16; d < c * 16 + 16; ++d) {
        unsigned int word;
        if (d >= 60) {
            word = __float_as_uint(b2[(q & 1) * 4 + (d - 60)]);
        } else {
            float v0 = 0.f, v1 = 0.f;
            if (d < 40) {
                int n = d >> 2, j0 = (d & 3) * 2;
                int hid = 32 * (n >> 1) + 8 * (m >> 2) + 4 * (n & 1) + (m & 3);
                if (hid < HDIM) {
                    #pragma unroll
                    for (int u = 0; u < 2; ++u) {
                        int j = j0 + u;
                        float v = 0.f;
                        if (j < 4)        v = sW[(4 * q + j) * HDIM + hid];
                        else if (j == 4) {
                            if      (q == 0) v = sW[16 * HDIM + hid];
                            else if (q == 1) v = sW[17 * HDIM + hid];
                            else if (q == 2) v = sW[2700 + hid];
                        }
                        if (u == 0) v0 = v; else v1 = v;
                    }
                }
            } else {
                int kt = (d - 40) >> 2, j0 = ((d - 40) & 3) * 2;
                int k0 = kt * 32 + q * 8 + j0, k1 = k0 + 1;
                if (m < 8) {
                    v0 = (k0 < HDIM) ? sW[2850 + k0 * 8 + m] : 0.f;
                    v1 = (k1 < HDIM) ? sW[2850 + k1 * 8 + m] : 0.f;
                }
            }
            __bf16 h0 = (__bf16)v0, h1 = (__bf16)v1;
            unsigned short u0, u1;
            __builtin_memcpy(&u0, &h0, 2);
            __builtin_memcpy(&u1, &h1, 2);
            word = (unsigned int)u0 | ((unsigned int)u1 << 16);
        }
        blob[(d >> 2) * 256 + lane * 4 + (d & 3)] = word;
    }
}

// ---------------------------------------------------------------------------
// Kernel 1: per-read MLP via bf16 MFMA, register-relay layer1->layer2.
// R9: divergence-free B-fragment. Lane (m,q) needs exactly ONE 16B granule
// of x (read m, floats 4q..4q+3 = granule g=4m+q) + one selected scalar
// (emb_x/emb_y/1/0 by q). All 64 lanes run the identical instruction stream.
// LDS slot s holds granule s ^ ((s>>3)&7)  (self-inverse XOR swizzle) ->
// readers' b128 pattern is 2-way bank-aliased only (free).
// ---------------------------------------------------------------------------
__global__ __launch_bounds__(256, 3) void k_readmlp(
    const float* __restrict__ x, const int* __restrict__ kmer,
    const float* __restrict__ emb, const unsigned int* __restrict__ blob,
    __bf16* __restrict__ h, int Ntot)
{
    __shared__ __align__(16) char smem[16384];   // 4 waves x 4KB x-tiles

    const int tid  = threadIdx.x;
    const int lane = tid & 63;
    const int wv   = tid >> 6;
    const int m    = lane & 15;
    const int q    = lane >> 4;

    // ---- fragment blob: 16 coalesced dwordx4 loads (L2-hot) ----
    uint4 B16[16];
    const uint4* bl = (const uint4*)blob;
#pragma unroll
    for (int i = 0; i < 16; ++i) B16[i] = bl[i * 64 + lane];
    const bf16x8* fr = (const bf16x8*)B16;       // fr[0..9]=fA1, fr[10..14]=fA2
    const float4 breg = ((const float4*)B16)[15];

    char* xbase = smem + wv * (T1 * 1024);
    const int waveBase = blockIdx.x * 256 + wv * 64;

    // ---- issue all 4 x-tile DMAs (lane fetches swizzled granule) ----
    const int gsw = lane ^ ((lane >> 3) & 7);
    const size_t xlimit = (size_t)Ntot * 64 - 16;
    const char* xg = (const char*)x;
#pragma unroll
    for (int t = 0; t < T1; ++t) {
        size_t off = (size_t)(waveBase + t * 16) * 64 + (size_t)gsw * 16;
        if (off > xlimit) off = xlimit;
        async_copy16(xg + off, xbase + t * 1024);
    }

    // ---- kmer -> emb for this wave's 64 reads, in registers ----
    const float2* emb2 = (const float2*)emb;
    int i0 = waveBase + lane; if (i0 >= Ntot) i0 = Ntot - 1;
    float2 e0 = emb2[kmer[i0]];

    // reader's LDS slot for granule 4m+q (2-way aliasing only)
    const int gidx = 4 * m + q;
    const int slot = gidx ^ ((gidx >> 3) & 7);

    const f32x4 zero = {0.f, 0.f, 0.f, 0.f};

#pragma unroll
    for (int t = 0; t < T1; ++t) {
        int src = (t << 4) + m;
        float ex = __shfl(e0.x, src);
        float ey = __shfl(e0.y, src);
        // slot-4 scalar by quad: q0=emb_x, q1=emb_y, q2=bias-1, q3=0
        float es = (q == 0) ? ex : (q == 1) ? ey : (q == 2) ? 1.0f : 0.0f;

        // input B-fragment, uniform across the wave
        const char* tb = xbase + t * 1024;
        f32x4 u = *(const f32x4*)(tb + (slot << 4));
        bf16x8 bin;
        bin[0] = (__bf16)u[0]; bin[1] = (__bf16)u[1];
        bin[2] = (__bf16)u[2]; bin[3] = (__bf16)u[3];
        bin[4] = (__bf16)es;
        bin[5] = (__bf16)0.f; bin[6] = (__bf16)0.f; bin[7] = (__bf16)0.f;

        // layer1 tile-pair -> relu/pack -> layer2, all in registers.
        f32x4 c2a = zero, c2b = zero;
#pragma unroll
        for (int kt = 0; kt < 5; ++kt) {
            f32x4 ca = __builtin_amdgcn_mfma_f32_16x16x32_bf16(fr[2 * kt],     bin, zero, 0, 0, 0);
            f32x4 cb = __builtin_amdgcn_mfma_f32_16x16x32_bf16(fr[2 * kt + 1], bin, zero, 0, 0, 0);
            bf16x8 bh;
            bh[0] = (__bf16)fmaxf(ca[0], 0.f); bh[1] = (__bf16)fmaxf(ca[1], 0.f);
            bh[2] = (__bf16)fmaxf(ca[2], 0.f); bh[3] = (__bf16)fmaxf(ca[3], 0.f);
            bh[4] = (__bf16)fmaxf(cb[0], 0.f); bh[5] = (__bf16)fmaxf(cb[1], 0.f);
            bh[6] = (__bf16)fmaxf(cb[2], 0.f); bh[7] = (__bf16)fmaxf(cb[3], 0.f);
            if (kt & 1) c2b = __builtin_amdgcn_mfma_f32_16x16x32_bf16(fr[10 + kt], bh, c2b, 0, 0, 0);
            else        c2a = __builtin_amdgcn_mfma_f32_16x16x32_bf16(fr[10 + kt], bh, c2a, 0, 0, 0);
        }

        int r = waveBase + t * 16 + m;
        if (q < 2 && r < Ntot) {
            bf16x4 o;
            o[0] = (__bf16)fmaxf(c2a[0] + c2b[0] + breg.x, 0.f);
            o[1] = (__bf16)fmaxf(c2a[1] + c2b[1] + breg.y, 0.f);
            o[2] = (__bf16)fmaxf(c2a[2] + c2b[2] + breg.z, 0.f);
            o[3] = (__bf16)fmaxf(c2a[3] + c2b[3] + breg.w, 0.f);
            *(bf16x4*)(h + (size_t)r * 8 + q * 4) = o;
        }
    }
}

// ---------------------------------------------------------------------------
// fully unrolled Batcher odd-even mergesort, n = 32
// ---------------------------------------------------------------------------
__device__ __forceinline__ void cswap(float& a, float& b) {
    float lo = fminf(a, b);
    float hi = fmaxf(a, b);
    a = lo; b = hi;
}

__device__ __forceinline__ void sort32(float v[32]) {
#pragma unroll
    for (int pp = 1; pp < 32; pp <<= 1) {
#pragma unroll
        for (int k = pp; k >= 1; k >>= 1) {
#pragma unroll
            for (int j = k & (pp - 1); j + k < 32; j += 2 * k) {
#pragma unroll
                for (int i = 0; i < k; ++i) {
                    if ((i + j) / (2 * pp) == (i + j + k) / (2 * pp))
                        cswap(v[i + j], v[i + j + k]);
                }
            }
        }
    }
}

// ---------------------------------------------------------------------------
// Kernel 2: per-site aggregation + head MLP (unchanged from R7).
// ---------------------------------------------------------------------------
__global__ __launch_bounds__(256) void k_site(
    const __bf16* __restrict__ hb, const int* __restrict__ indices,
    const float* __restrict__ W3, const float* __restrict__ b3,
    const float* __restrict__ W4, const float* __restrict__ b4,
    float* __restrict__ out, int Gtot)
{
    __shared__ int    sIdx[32 * 33];        // 4.2 KB
    __shared__ __align__(16) __bf16 sH[32 * 264];  // 16.9 KB
    __shared__ __bf16 sW3B[HDIM * 48];      // 14.4 KB
    __shared__ float  sB3[HDIM];
    __shared__ float  sW4[HDIM];
    __shared__ float  sAgg[32 * 44];        // 5.6 KB

    const int tid  = threadIdx.x;
    const int gblk = blockIdx.x * 32;

    for (int e = tid; e < 1024; e += 256) {
        int g = e >> 5;
        sIdx[g * 33 + (e & 31)] = (gblk + g < Gtot) ? indices[(size_t)gblk * 32 + e] : 0;
    }
    __syncthreads();

    for (int e = tid; e < 1024; e += 256) {
        int g = e >> 5, mm = e & 31;
        int r = sIdx[g * 33 + mm];
        *(uint4*)(&sH[g * 264 + mm * 8]) = *(const uint4*)(hb + (size_t)r * 8);
    }

    for (int e = tid; e < 40 * HDIM; e += 256) {
        int c = e / HDIM, j = e - c * HDIM;     // W3 row-major [40][150]
        sW3B[j * 48 + c] = (__bf16)W3[e];
    }
    for (int e = tid; e < HDIM; e += 256) { sB3[e] = b3[e]; sW4[e] = W4[e]; }
    __syncthreads();

    const int g = tid >> 3, p = tid & 7;
    {
        float v[32];
#pragma unroll
        for (int mm = 0; mm < 32; ++mm)
            v[mm] = (float)sH[g * 264 + mm * 8 + p];

        float sum = 0.f, sumsq = 0.f, mn = v[0], mx = v[0];
#pragma unroll
        for (int mm = 0; mm < 32; ++mm) {
            sum += v[mm];
            sumsq = fmaf(v[mm], v[mm], sumsq);
            mn = fminf(mn, v[mm]);
            mx = fmaxf(mx, v[mm]);
        }
        float mean = sum * (1.f / 32.f);
        float var  = fmaxf((sumsq - 32.f * mean * mean) * (1.f / 31.f), 0.f);
        sort32(v);
        sAgg[g * 44 + 0 * 8 + p] = mean;
        sAgg[g * 44 + 1 * 8 + p] = var;
        sAgg[g * 44 + 2 * 8 + p] = mn;
        sAgg[g * 44 + 3 * 8 + p] = v[15];   // lower median
        sAgg[g * 44 + 4 * 8 + p] = mx;
    }
    __syncthreads();

    float ag[40];
#pragma unroll
    for (int c4 = 0; c4 < 10; ++c4) {
        float4 tq = *(const float4*)(sAgg + g * 44 + c4 * 4);
        ag[c4 * 4 + 0] = tq.x; ag[c4 * 4 + 1] = tq.y;
        ag[c4 * 4 + 2] = tq.z; ag[c4 * 4 + 3] = tq.w;
    }

    float acc = 0.f;
    for (int j = p; j < HDIM; j += 8) {
        const __bf16* wr = sW3B + j * 48;
        float z = sB3[j];
#pragma unroll
        for (int c8 = 0; c8 < 5; ++c8) {
            bf16x8 w = *(const bf16x8*)(wr + c8 * 8);
#pragma unroll
            for (int u = 0; u < 8; ++u)
                z = fmaf(ag[c8 * 8 + u], (float)w[u], z);
        }
        z = fmaxf(z, 0.f);
        acc = fmaf(z, sW4[j], acc);
    }
    acc += __shfl_xor(acc, 1);
    acc += __shfl_xor(acc, 2);
    acc += __shfl_xor(acc, 4);

    if (p == 0 && gblk + g < Gtot) {
        float zf = acc + b4[0];
        out[gblk + g] = 1.f / (1.f + expf(-zf));
    }
}

// ---------------------------------------------------------------------------
extern "C" void kernel_launch(void* const* d_in, const int* in_sizes, int n_in,
                              void* d_out, int out_size, void* d_ws, size_t ws_size,
                              hipStream_t stream) {
    const float* x       = (const float*)d_in[0];
    const int*   kmer    = (const int*)  d_in[1];
    const int*   indices = (const int*)  d_in[2];
    const float* emb     = (const float*)d_in[3];
    const float* W1      = (const float*)d_in[4];
    const float* b1      = (const float*)d_in[5];
    const float* W2      = (const float*)d_in[6];
    const float* b2      = (const float*)d_in[7];
    const float* W3      = (const float*)d_in[8];
    const float* b3      = (const float*)d_in[9];
    const float* W4      = (const float*)d_in[10];
    const float* b4      = (const float*)d_in[11];

    float*  out = (float*)d_out;
    __bf16* h   = (__bf16*)d_ws;                       // [N,8] bf16 = 16 MB
    unsigned int* blob = (unsigned int*)((char*)d_ws + (16u << 20));  // 16 KB

    const int N = in_sizes[1];
    const int G = out_size;

    k_pack<<<1, 256, 0, stream>>>(W1, b1, W2, b2, blob);

    const int grid1 = (N + 255) / 256;    // 256 reads / block (4 waves x 4 x 16)
    k_readmlp<<<grid1, 256, 0, stream>>>(x, kmer, emb, blob, h, N);

    const int grid2 = (G + 31) / 32;
    k_site<<<grid2, 256, 0, stream>>>(h, indices, W3, b3, W4, b4, out, G);
}